// Round 1
// baseline (255.750 us; speedup 1.0000x reference)
//
#include <hip/hip_runtime.h>

#define B_ 8
#define C_ 64
#define H_ 128
#define W_ 128
#define HW_ (H_ * W_)

// ---------------------------------------------------------------------------
// K1: fused QKV 1x1-conv projection.
// x: [B][C][H][W] fp32.  Weights: [64][64] row-major (o,c).
// Output layout for q/k/v: [B][4 chunk][H][W][16]  (16-channel pixel vectors,
// chunk-major) so K2 reads/stages are perfectly coalesced.
// grid (W/64=2, H=128, B=8), block 256.
// Per block: 64 pixels. wave-lane = output channel o (64), thread-group g
// (t>>6) owns 16 pixels. x tile staged in LDS [64 pix][68 pad ch].
// ---------------------------------------------------------------------------
__global__ __launch_bounds__(256) void proj_qkv(
    const float* __restrict__ x, const float* __restrict__ w1,
    const float* __restrict__ w2, const float* __restrict__ w3,
    float* __restrict__ q, float* __restrict__ k, float* __restrict__ v)
{
    __shared__ float xs[64 * 68];  // [pixel][channel], pad 68 to spread banks
    const int b = blockIdx.z, h = blockIdx.y, w0 = blockIdx.x * 64;
    const int t = threadIdx.x;
    const int lane = t & 63, g = t >> 6;

    // stage x: 64 channels x 64 pixels, coalesced over w
    const float* xb = x + (size_t)b * C_ * HW_ + (size_t)h * W_ + w0;
    #pragma unroll
    for (int cc = 0; cc < 16; ++cc) {
        const int c = cc * 4 + g;
        xs[lane * 68 + c] = xb[(size_t)c * HW_ + lane];
    }
    __syncthreads();

    const int o = lane;  // wave-lane = output channel
    float aq[16], ak[16], av[16];
    #pragma unroll
    for (int p = 0; p < 16; ++p) { aq[p] = 0.f; ak[p] = 0.f; av[p] = 0.f; }

    #pragma unroll 4
    for (int c4 = 0; c4 < 16; ++c4) {
        const float4 f1 = *(const float4*)(w1 + o * 64 + c4 * 4);
        const float4 f2 = *(const float4*)(w2 + o * 64 + c4 * 4);
        const float4 f3 = *(const float4*)(w3 + o * 64 + c4 * 4);
        #pragma unroll
        for (int p = 0; p < 16; ++p) {
            const float4 xv = *(const float4*)(xs + (g * 16 + p) * 68 + c4 * 4);
            aq[p] += f1.x * xv.x + f1.y * xv.y + f1.z * xv.z + f1.w * xv.w;
            ak[p] += f2.x * xv.x + f2.y * xv.y + f2.z * xv.z + f2.w * xv.w;
            av[p] += f3.x * xv.x + f3.y * xv.y + f3.z * xv.z + f3.w * xv.w;
        }
    }

    // write: [B][chunk=o>>4][H][W][16], lanes o give coalesced 64B segments
    const int chunk = o >> 4, oi = o & 15;
    const size_t base =
        ((((size_t)b * 4 + chunk) * H_ + h) * W_ + w0) * 16 + oi;
    #pragma unroll
    for (int p = 0; p < 16; ++p) {
        const size_t a = base + (size_t)(g * 16 + p) * 16;
        q[a] = aq[p];
        k[a] = ak[p];
        v[a] = av[p];
    }
}

// ---------------------------------------------------------------------------
// K2: fused local attention. One thread per output pixel, 16x16 tile/block.
// Scores accumulated over 4 channel-chunks of 16 (k halo tile in LDS),
// softmax in registers (49 weights), then weighting over 4 chunks (v halo
// tile reuses same LDS buffer). Zero-filled OOB halo == reference zero-pad.
// LDS tile: [22*22 pix][16 ch pad 20] fp32 = 38.7 KB -> 4 blocks/CU.
// grid (8, 8, 8), block 256.
// ---------------------------------------------------------------------------
__global__ __launch_bounds__(256) void local_attn(
    const float* __restrict__ q, const float* __restrict__ k,
    const float* __restrict__ v, float* __restrict__ out)
{
    __shared__ float tile[484 * 20];  // pad stride 20 words: 8 bank-starts
    const int b = blockIdx.z, h0 = blockIdx.y * 16, w0 = blockIdx.x * 16;
    const int t = threadIdx.x;
    const int pw = t & 15, ph = t >> 4;

    float sc[49];
    #pragma unroll
    for (int i = 0; i < 49; ++i) sc[i] = 0.f;

    // ---- phase 1: scores ----
    for (int chunk = 0; chunk < 4; ++chunk) {
        const float* kc = k + ((size_t)b * 4 + chunk) * HW_ * 16;
        for (int i = t; i < 484 * 4; i += 256) {
            const int pix = i >> 2, c4 = i & 3;
            const int r = pix / 22, cl = pix - r * 22;
            const int gh = h0 + r - 3, gw = w0 + cl - 3;
            float4 val = make_float4(0.f, 0.f, 0.f, 0.f);
            if (gh >= 0 && gh < H_ && gw >= 0 && gw < W_)
                val = *(const float4*)(kc + ((size_t)gh * W_ + gw) * 16 + c4 * 4);
            *(float4*)(tile + pix * 20 + c4 * 4) = val;
        }
        const float* qp =
            q + (((size_t)b * 4 + chunk) * HW_ + (size_t)(h0 + ph) * W_ + (w0 + pw)) * 16;
        const float4 q0 = ((const float4*)qp)[0];
        const float4 q1 = ((const float4*)qp)[1];
        const float4 q2 = ((const float4*)qp)[2];
        const float4 q3 = ((const float4*)qp)[3];
        __syncthreads();
        #pragma unroll
        for (int dh = 0; dh < 7; ++dh) {
            #pragma unroll
            for (int dw = 0; dw < 7; ++dw) {
                const float* kp = tile + ((ph + dh) * 22 + (pw + dw)) * 20;
                const float4 k0 = ((const float4*)kp)[0];
                const float4 k1 = ((const float4*)kp)[1];
                const float4 k2 = ((const float4*)kp)[2];
                const float4 k3 = ((const float4*)kp)[3];
                sc[dh * 7 + dw] +=
                    q0.x * k0.x + q0.y * k0.y + q0.z * k0.z + q0.w * k0.w +
                    q1.x * k1.x + q1.y * k1.y + q1.z * k1.z + q1.w * k1.w +
                    q2.x * k2.x + q2.y * k2.y + q2.z * k2.z + q2.w * k2.w +
                    q3.x * k3.x + q3.y * k3.y + q3.z * k3.z + q3.w * k3.w;
            }
        }
        __syncthreads();
    }

    // ---- softmax over 49 (max-subtracted, matches jax.nn.softmax) ----
    float m = sc[0];
    #pragma unroll
    for (int i = 1; i < 49; ++i) m = fmaxf(m, sc[i]);
    float s = 0.f;
    #pragma unroll
    for (int i = 0; i < 49; ++i) { sc[i] = __expf(sc[i] - m); s += sc[i]; }
    const float inv = 1.f / s;
    #pragma unroll
    for (int i = 0; i < 49; ++i) sc[i] *= inv;

    // ---- phase 2: weighting ----
    for (int chunk = 0; chunk < 4; ++chunk) {
        const float* vc = v + ((size_t)b * 4 + chunk) * HW_ * 16;
        for (int i = t; i < 484 * 4; i += 256) {
            const int pix = i >> 2, c4 = i & 3;
            const int r = pix / 22, cl = pix - r * 22;
            const int gh = h0 + r - 3, gw = w0 + cl - 3;
            float4 val = make_float4(0.f, 0.f, 0.f, 0.f);
            if (gh >= 0 && gh < H_ && gw >= 0 && gw < W_)
                val = *(const float4*)(vc + ((size_t)gh * W_ + gw) * 16 + c4 * 4);
            *(float4*)(tile + pix * 20 + c4 * 4) = val;
        }
        __syncthreads();
        float4 a0 = make_float4(0.f, 0.f, 0.f, 0.f);
        float4 a1 = make_float4(0.f, 0.f, 0.f, 0.f);
        float4 a2 = make_float4(0.f, 0.f, 0.f, 0.f);
        float4 a3 = make_float4(0.f, 0.f, 0.f, 0.f);
        #pragma unroll
        for (int dh = 0; dh < 7; ++dh) {
            #pragma unroll
            for (int dw = 0; dw < 7; ++dw) {
                const float wgt = sc[dh * 7 + dw];
                const float* vp = tile + ((ph + dh) * 22 + (pw + dw)) * 20;
                const float4 v0 = ((const float4*)vp)[0];
                const float4 v1 = ((const float4*)vp)[1];
                const float4 v2 = ((const float4*)vp)[2];
                const float4 v3 = ((const float4*)vp)[3];
                a0.x += wgt * v0.x; a0.y += wgt * v0.y; a0.z += wgt * v0.z; a0.w += wgt * v0.w;
                a1.x += wgt * v1.x; a1.y += wgt * v1.y; a1.z += wgt * v1.z; a1.w += wgt * v1.w;
                a2.x += wgt * v2.x; a2.y += wgt * v2.y; a2.z += wgt * v2.z; a2.w += wgt * v2.w;
                a3.x += wgt * v3.x; a3.y += wgt * v3.y; a3.z += wgt * v3.z; a3.w += wgt * v3.w;
            }
        }
        // out: [B][64][H][W], o = chunk*16 + c; lanes pw -> 64B segments
        const size_t ob = ((size_t)b * 64 + chunk * 16) * HW_ +
                          (size_t)(h0 + ph) * W_ + (w0 + pw);
        out[ob + (size_t)0  * HW_] = a0.x;
        out[ob + (size_t)1  * HW_] = a0.y;
        out[ob + (size_t)2  * HW_] = a0.z;
        out[ob + (size_t)3  * HW_] = a0.w;
        out[ob + (size_t)4  * HW_] = a1.x;
        out[ob + (size_t)5  * HW_] = a1.y;
        out[ob + (size_t)6  * HW_] = a1.z;
        out[ob + (size_t)7  * HW_] = a1.w;
        out[ob + (size_t)8  * HW_] = a2.x;
        out[ob + (size_t)9  * HW_] = a2.y;
        out[ob + (size_t)10 * HW_] = a2.z;
        out[ob + (size_t)11 * HW_] = a2.w;
        out[ob + (size_t)12 * HW_] = a3.x;
        out[ob + (size_t)13 * HW_] = a3.y;
        out[ob + (size_t)14 * HW_] = a3.z;
        out[ob + (size_t)15 * HW_] = a3.w;
        __syncthreads();
    }
}

extern "C" void kernel_launch(void* const* d_in, const int* in_sizes, int n_in,
                              void* d_out, int out_size, void* d_ws, size_t ws_size,
                              hipStream_t stream) {
    const float* x  = (const float*)d_in[0];
    const float* w1 = (const float*)d_in[1];
    const float* w2 = (const float*)d_in[2];
    const float* w3 = (const float*)d_in[3];
    // d_in[4], d_in[5] are kH=7, kW=7 (fixed by setup_inputs; hardcoded).

    // workspace: q, k, v each B*4*HW*16 = 8388608 floats (33.55 MB), 100.7 MB total
    float* q = (float*)d_ws;
    float* k = q + (size_t)B_ * 4 * HW_ * 16;
    float* v = k + (size_t)B_ * 4 * HW_ * 16;
    float* o = (float*)d_out;

    proj_qkv<<<dim3(2, H_, B_), 256, 0, stream>>>(x, w1, w2, w3, q, k, v);
    local_attn<<<dim3(8, 8, 8), 256, 0, stream>>>(q, k, v, o);
}

// Round 2
// 247.143 us; speedup vs baseline: 1.0348x; 1.0348x over previous
//
#include <hip/hip_runtime.h>

#define B_ 8
#define C_ 64
#define H_ 128
#define W_ 128
#define HW_ (H_ * W_)

// ---------------------------------------------------------------------------
// K1: fused QKV 1x1-conv projection. Thread = pixel, no LDS.
// x: [B][C][H][W]. Each thread holds x[px][0:64] in 64 VGPRs (coalesced b32
// loads, lane = consecutive w). Weight rows are wave-uniform (o = loop var)
// -> s_load broadcast, FMA with SGPR operand. 6 independent acc chains.
// Output q/k/v layout: [B][4 chunk][H*W][16] (16-ch pixel vectors) -> b128
// stores, and K2 staging reads are contiguous.
// grid (HW/256, B), block 256.
// ---------------------------------------------------------------------------
__global__ __launch_bounds__(256) void proj_qkv(
    const float* __restrict__ x, const float* __restrict__ w1,
    const float* __restrict__ w2, const float* __restrict__ w3,
    float* __restrict__ q, float* __restrict__ k, float* __restrict__ v)
{
    const int px = blockIdx.x * 256 + threadIdx.x;
    const int b  = blockIdx.y;
    const float* xb = x + (size_t)b * C_ * HW_ + px;

    float xv[64];
    #pragma unroll
    for (int c = 0; c < 64; ++c) xv[c] = xb[(size_t)c * HW_];

    for (int chunk = 0; chunk < 4; ++chunk) {
        float oq[16], ok[16], ov[16];
        #pragma unroll 2
        for (int oi = 0; oi < 16; ++oi) {
            const int o = chunk * 16 + oi;
            const float* __restrict__ r1 = w1 + o * 64;
            const float* __restrict__ r2 = w2 + o * 64;
            const float* __restrict__ r3 = w3 + o * 64;
            float aq0 = 0.f, aq1 = 0.f, ak0 = 0.f, ak1 = 0.f, av0 = 0.f, av1 = 0.f;
            #pragma unroll
            for (int c = 0; c < 64; c += 2) {
                aq0 += r1[c]     * xv[c];
                aq1 += r1[c + 1] * xv[c + 1];
                ak0 += r2[c]     * xv[c];
                ak1 += r2[c + 1] * xv[c + 1];
                av0 += r3[c]     * xv[c];
                av1 += r3[c + 1] * xv[c + 1];
            }
            oq[oi] = aq0 + aq1;
            ok[oi] = ak0 + ak1;
            ov[oi] = av0 + av1;
        }
        const size_t base = (((size_t)b * 4 + chunk) * HW_ + px) * 16;
        #pragma unroll
        for (int j = 0; j < 4; ++j) {
            *(float4*)(q + base + j * 4) =
                make_float4(oq[j*4], oq[j*4+1], oq[j*4+2], oq[j*4+3]);
            *(float4*)(k + base + j * 4) =
                make_float4(ok[j*4], ok[j*4+1], ok[j*4+2], ok[j*4+3]);
            *(float4*)(v + base + j * 4) =
                make_float4(ov[j*4], ov[j*4+1], ov[j*4+2], ov[j*4+3]);
        }
    }
}

// ---------------------------------------------------------------------------
// K2: fused local attention, 16x16 pixel tile per block, thread = pixel.
// LDS tile is PLANE-MAJOR: tile[c4 plane][pix*4 + 0..3], plane stride
// 484*4+8 = 1944 words, so plane bases mod 32 = {0,24,16,8}. Compute-phase
// b128 reads have lane address stride 4 words -> the free 2-way minimum
// (no 8-way serialization like the old [pix][ch] stride-20 layout).
// grid (8, 8, 8), block 256. LDS 31.1 KB -> 5 blocks/CU.
// ---------------------------------------------------------------------------
#define PLANE_ (484 * 4 + 8)   // words per c4 plane (1944)

__global__ __launch_bounds__(256) void local_attn(
    const float* __restrict__ q, const float* __restrict__ k,
    const float* __restrict__ v, float* __restrict__ out)
{
    __shared__ float tile[4 * PLANE_];
    const int b = blockIdx.z, h0 = blockIdx.y * 16, w0 = blockIdx.x * 16;
    const int t = threadIdx.x;
    const int pw = t & 15, ph = t >> 4;

    float sc[49];
    #pragma unroll
    for (int i = 0; i < 49; ++i) sc[i] = 0.f;

    // ---- phase 1: scores ----
    for (int chunk = 0; chunk < 4; ++chunk) {
        const float* kc = k + ((size_t)b * 4 + chunk) * HW_ * 16;
        for (int i = t; i < 484 * 4; i += 256) {
            const int pix = i >> 2, c4 = i & 3;
            const int r = pix / 22, cl = pix - r * 22;
            const int gh = h0 + r - 3, gw = w0 + cl - 3;
            float4 val = make_float4(0.f, 0.f, 0.f, 0.f);
            if (gh >= 0 && gh < H_ && gw >= 0 && gw < W_)
                val = *(const float4*)(kc + ((size_t)gh * W_ + gw) * 16 + c4 * 4);
            *(float4*)(tile + c4 * PLANE_ + pix * 4) = val;
        }
        const float* qp =
            q + (((size_t)b * 4 + chunk) * HW_ + (size_t)(h0 + ph) * W_ + (w0 + pw)) * 16;
        const float4 q0 = ((const float4*)qp)[0];
        const float4 q1 = ((const float4*)qp)[1];
        const float4 q2 = ((const float4*)qp)[2];
        const float4 q3 = ((const float4*)qp)[3];
        __syncthreads();
        #pragma unroll
        for (int dh = 0; dh < 7; ++dh) {
            #pragma unroll
            for (int dw = 0; dw < 7; ++dw) {
                const int np = ((ph + dh) * 22 + (pw + dw)) * 4;
                const float4 k0 = *(const float4*)(tile + 0 * PLANE_ + np);
                const float4 k1 = *(const float4*)(tile + 1 * PLANE_ + np);
                const float4 k2 = *(const float4*)(tile + 2 * PLANE_ + np);
                const float4 k3 = *(const float4*)(tile + 3 * PLANE_ + np);
                sc[dh * 7 + dw] +=
                    q0.x * k0.x + q0.y * k0.y + q0.z * k0.z + q0.w * k0.w +
                    q1.x * k1.x + q1.y * k1.y + q1.z * k1.z + q1.w * k1.w +
                    q2.x * k2.x + q2.y * k2.y + q2.z * k2.z + q2.w * k2.w +
                    q3.x * k3.x + q3.y * k3.y + q3.z * k3.z + q3.w * k3.w;
            }
        }
        __syncthreads();
    }

    // ---- softmax over 49 ----
    float m = sc[0];
    #pragma unroll
    for (int i = 1; i < 49; ++i) m = fmaxf(m, sc[i]);
    float s = 0.f;
    #pragma unroll
    for (int i = 0; i < 49; ++i) { sc[i] = __expf(sc[i] - m); s += sc[i]; }
    const float inv = 1.f / s;
    #pragma unroll
    for (int i = 0; i < 49; ++i) sc[i] *= inv;

    // ---- phase 2: weighting ----
    for (int chunk = 0; chunk < 4; ++chunk) {
        const float* vc = v + ((size_t)b * 4 + chunk) * HW_ * 16;
        for (int i = t; i < 484 * 4; i += 256) {
            const int pix = i >> 2, c4 = i & 3;
            const int r = pix / 22, cl = pix - r * 22;
            const int gh = h0 + r - 3, gw = w0 + cl - 3;
            float4 val = make_float4(0.f, 0.f, 0.f, 0.f);
            if (gh >= 0 && gh < H_ && gw >= 0 && gw < W_)
                val = *(const float4*)(vc + ((size_t)gh * W_ + gw) * 16 + c4 * 4);
            *(float4*)(tile + c4 * PLANE_ + pix * 4) = val;
        }
        __syncthreads();
        float4 a0 = make_float4(0.f, 0.f, 0.f, 0.f);
        float4 a1 = make_float4(0.f, 0.f, 0.f, 0.f);
        float4 a2 = make_float4(0.f, 0.f, 0.f, 0.f);
        float4 a3 = make_float4(0.f, 0.f, 0.f, 0.f);
        #pragma unroll
        for (int dh = 0; dh < 7; ++dh) {
            #pragma unroll
            for (int dw = 0; dw < 7; ++dw) {
                const float wgt = sc[dh * 7 + dw];
                const int np = ((ph + dh) * 22 + (pw + dw)) * 4;
                const float4 v0 = *(const float4*)(tile + 0 * PLANE_ + np);
                const float4 v1 = *(const float4*)(tile + 1 * PLANE_ + np);
                const float4 v2 = *(const float4*)(tile + 2 * PLANE_ + np);
                const float4 v3 = *(const float4*)(tile + 3 * PLANE_ + np);
                a0.x += wgt * v0.x; a0.y += wgt * v0.y; a0.z += wgt * v0.z; a0.w += wgt * v0.w;
                a1.x += wgt * v1.x; a1.y += wgt * v1.y; a1.z += wgt * v1.z; a1.w += wgt * v1.w;
                a2.x += wgt * v2.x; a2.y += wgt * v2.y; a2.z += wgt * v2.z; a2.w += wgt * v2.w;
                a3.x += wgt * v3.x; a3.y += wgt * v3.y; a3.z += wgt * v3.z; a3.w += wgt * v3.w;
            }
        }
        const size_t ob = ((size_t)b * 64 + chunk * 16) * HW_ +
                          (size_t)(h0 + ph) * W_ + (w0 + pw);
        out[ob + (size_t)0  * HW_] = a0.x;
        out[ob + (size_t)1  * HW_] = a0.y;
        out[ob + (size_t)2  * HW_] = a0.z;
        out[ob + (size_t)3  * HW_] = a0.w;
        out[ob + (size_t)4  * HW_] = a1.x;
        out[ob + (size_t)5  * HW_] = a1.y;
        out[ob + (size_t)6  * HW_] = a1.z;
        out[ob + (size_t)7  * HW_] = a1.w;
        out[ob + (size_t)8  * HW_] = a2.x;
        out[ob + (size_t)9  * HW_] = a2.y;
        out[ob + (size_t)10 * HW_] = a2.z;
        out[ob + (size_t)11 * HW_] = a2.w;
        out[ob + (size_t)12 * HW_] = a3.x;
        out[ob + (size_t)13 * HW_] = a3.y;
        out[ob + (size_t)14 * HW_] = a3.z;
        out[ob + (size_t)15 * HW_] = a3.w;
        __syncthreads();
    }
}

extern "C" void kernel_launch(void* const* d_in, const int* in_sizes, int n_in,
                              void* d_out, int out_size, void* d_ws, size_t ws_size,
                              hipStream_t stream) {
    const float* x  = (const float*)d_in[0];
    const float* w1 = (const float*)d_in[1];
    const float* w2 = (const float*)d_in[2];
    const float* w3 = (const float*)d_in[3];

    float* q = (float*)d_ws;
    float* k = q + (size_t)B_ * 4 * HW_ * 16;
    float* v = k + (size_t)B_ * 4 * HW_ * 16;
    float* o = (float*)d_out;

    proj_qkv<<<dim3(HW_ / 256, B_), 256, 0, stream>>>(x, w1, w2, w3, q, k, v);
    local_attn<<<dim3(8, 8, 8), 256, 0, stream>>>(q, k, v, o);
}